// Round 1
// baseline (127.231 us; speedup 1.0000x reference)
//
#include <hip/hip_runtime.h>

#define NROWS 16384
#define DIM   1024
#define MARGIN_F 1.0f
#define EPS_F 1e-6f

// One block (256 threads) per row. Each thread owns 4 consecutive floats of
// rows i, pos[i], neg[i] (float4 loads, kept in registers across both passes).
__global__ __launch_bounds__(256) void row_loss_kernel(
    const float* __restrict__ emb,
    const int*   __restrict__ pos_idx,
    const int*   __restrict__ neg_idx,
    float*       __restrict__ losses)
{
    const int row  = blockIdx.x;
    const int tid  = threadIdx.x;
    const int lane = tid & 63;
    const int wid  = tid >> 6;

    const int p = pos_idx[row];
    const int n = neg_idx[row];

    const float4* xi = (const float4*)(emb + (size_t)row * DIM);
    const float4* xp = (const float4*)(emb + (size_t)p   * DIM);
    const float4* xn = (const float4*)(emb + (size_t)n   * DIM);

    const float4 a = xi[tid];
    const float4 b = xp[tid];
    const float4 c = xn[tid];

    // ---- pass 1: squared norms of the three rows ----
    float ni = a.x*a.x + a.y*a.y + a.z*a.z + a.w*a.w;
    float np_ = b.x*b.x + b.y*b.y + b.z*b.z + b.w*b.w;
    float nn = c.x*c.x + c.y*c.y + c.z*c.z + c.w*c.w;

    #pragma unroll
    for (int off = 32; off > 0; off >>= 1) {
        ni  += __shfl_down(ni,  off, 64);
        np_ += __shfl_down(np_, off, 64);
        nn  += __shfl_down(nn,  off, 64);
    }

    __shared__ float sm[3][4];
    __shared__ float scales[3];
    if (lane == 0) { sm[0][wid] = ni; sm[1][wid] = np_; sm[2][wid] = nn; }
    __syncthreads();
    if (tid == 0) {
        float si = sm[0][0] + sm[0][1] + sm[0][2] + sm[0][3];
        float sp = sm[1][0] + sm[1][1] + sm[1][2] + sm[1][3];
        float sn = sm[2][0] + sm[2][1] + sm[2][2] + sm[2][3];
        scales[0] = 1.0f / fmaxf(sqrtf(si), EPS_F);
        scales[1] = 1.0f / fmaxf(sqrtf(sp), EPS_F);
        scales[2] = 1.0f / fmaxf(sqrtf(sn), EPS_F);
    }
    __syncthreads();
    const float si = scales[0];
    const float sp = scales[1];
    const float sn = scales[2];

    // ---- pass 2: pairwise squared distances (from registers) ----
    float sum_p = 0.0f, sum_n = 0.0f;
    {
        float t;
        t = a.x*si - b.x*sp + EPS_F; sum_p += t*t;
        t = a.y*si - b.y*sp + EPS_F; sum_p += t*t;
        t = a.z*si - b.z*sp + EPS_F; sum_p += t*t;
        t = a.w*si - b.w*sp + EPS_F; sum_p += t*t;
        t = a.x*si - c.x*sn + EPS_F; sum_n += t*t;
        t = a.y*si - c.y*sn + EPS_F; sum_n += t*t;
        t = a.z*si - c.z*sn + EPS_F; sum_n += t*t;
        t = a.w*si - c.w*sn + EPS_F; sum_n += t*t;
    }

    #pragma unroll
    for (int off = 32; off > 0; off >>= 1) {
        sum_p += __shfl_down(sum_p, off, 64);
        sum_n += __shfl_down(sum_n, off, 64);
    }
    // sm reuse is safe: phase-1 reads of sm happen before the barrier above.
    if (lane == 0) { sm[0][wid] = sum_p; sm[1][wid] = sum_n; }
    __syncthreads();
    if (tid == 0) {
        float s_pos = sm[0][0] + sm[0][1] + sm[0][2] + sm[0][3];
        float s_neg = sm[1][0] + sm[1][1] + sm[1][2] + sm[1][3];
        float d_pos = sqrtf(s_pos) + EPS_F;
        float d_neg = sqrtf(s_neg) + EPS_F;
        float pl = d_pos * d_pos;
        float mq = fmaxf(MARGIN_F - d_neg, EPS_F);
        float nl = mq * mq;
        losses[row] = pl + nl;
    }
}

__global__ __launch_bounds__(256) void final_reduce_kernel(
    const float* __restrict__ losses,
    float*       __restrict__ out)
{
    const int tid  = threadIdx.x;
    const int lane = tid & 63;
    const int wid  = tid >> 6;

    float s = 0.0f;
    for (int i = tid; i < NROWS; i += 256) s += losses[i];

    #pragma unroll
    for (int off = 32; off > 0; off >>= 1) s += __shfl_down(s, off, 64);

    __shared__ float sm[4];
    if (lane == 0) sm[wid] = s;
    __syncthreads();
    if (tid == 0) {
        float total = sm[0] + sm[1] + sm[2] + sm[3];
        out[0] = total / (2.0f * (float)NROWS);
    }
}

extern "C" void kernel_launch(void* const* d_in, const int* in_sizes, int n_in,
                              void* d_out, int out_size, void* d_ws, size_t ws_size,
                              hipStream_t stream) {
    const float* emb = (const float*)d_in[0];
    // d_in[1] = labels (unused by the loss itself)
    const int* pos = (const int*)d_in[2];
    const int* neg = (const int*)d_in[3];

    float* losses = (float*)d_ws;          // NROWS floats of scratch
    float* out    = (float*)d_out;

    row_loss_kernel<<<NROWS, 256, 0, stream>>>(emb, pos, neg, losses);
    final_reduce_kernel<<<1, 256, 0, stream>>>(losses, out);
}

// Round 2
// 110.789 us; speedup vs baseline: 1.1484x; 1.1484x over previous
//
#include <hip/hip_runtime.h>

#define NROWS 16384
#define DIM   1024          // floats per row
#define F4_PER_ROW 256      // DIM/4
#define F4_PER_LANE 4       // F4_PER_ROW/64
#define MARGIN_F 1.0f
#define EPS_F 1e-6f

// One WAVE (64 lanes) per row; 4 rows per 256-thread block. Each lane loads
// 4 coalesced float4 per row for each of {anchor, pos, neg} (12 independent
// 16B loads in flight). All reductions are __shfl_xor butterflies: no LDS,
// no __syncthreads — waves in a block proceed independently.
__global__ __launch_bounds__(256) void row_loss_kernel(
    const float* __restrict__ emb,
    const int*   __restrict__ pos_idx,
    const int*   __restrict__ neg_idx,
    float*       __restrict__ losses)
{
    const int tid  = threadIdx.x;
    const int lane = tid & 63;
    const int wid  = tid >> 6;
    const int row  = blockIdx.x * 4 + wid;

    const int p = pos_idx[row];
    const int n = neg_idx[row];

    const float4* xi = (const float4*)(emb + (size_t)row * DIM);
    const float4* xp = (const float4*)(emb + (size_t)p   * DIM);
    const float4* xn = (const float4*)(emb + (size_t)n   * DIM);

    // 12 independent coalesced loads (lane-consecutive within each 1 KiB chunk)
    float4 a[F4_PER_LANE], b[F4_PER_LANE], c[F4_PER_LANE];
    #pragma unroll
    for (int j = 0; j < F4_PER_LANE; ++j) {
        a[j] = xi[lane + 64 * j];
        b[j] = xp[lane + 64 * j];
        c[j] = xn[lane + 64 * j];
    }

    // ---- pass 1: squared norms (three interleaved chains) ----
    float ni = 0.f, np_ = 0.f, nn = 0.f;
    #pragma unroll
    for (int j = 0; j < F4_PER_LANE; ++j) {
        ni  = fmaf(a[j].x, a[j].x, ni);  ni  = fmaf(a[j].y, a[j].y, ni);
        ni  = fmaf(a[j].z, a[j].z, ni);  ni  = fmaf(a[j].w, a[j].w, ni);
        np_ = fmaf(b[j].x, b[j].x, np_); np_ = fmaf(b[j].y, b[j].y, np_);
        np_ = fmaf(b[j].z, b[j].z, np_); np_ = fmaf(b[j].w, b[j].w, np_);
        nn  = fmaf(c[j].x, c[j].x, nn);  nn  = fmaf(c[j].y, c[j].y, nn);
        nn  = fmaf(c[j].z, c[j].z, nn);  nn  = fmaf(c[j].w, c[j].w, nn);
    }
    // butterfly: every lane ends with the full sum (no broadcast needed)
    #pragma unroll
    for (int m = 1; m < 64; m <<= 1) {
        ni  += __shfl_xor(ni,  m, 64);
        np_ += __shfl_xor(np_, m, 64);
        nn  += __shfl_xor(nn,  m, 64);
    }
    const float si = 1.0f / fmaxf(sqrtf(ni),  EPS_F);
    const float sp = 1.0f / fmaxf(sqrtf(np_), EPS_F);
    const float sn = 1.0f / fmaxf(sqrtf(nn),  EPS_F);

    // ---- pass 2: squared pairwise distances (from registers) ----
    float sum_p = 0.f, sum_n = 0.f;
    #pragma unroll
    for (int j = 0; j < F4_PER_LANE; ++j) {
        float t;
        t = fmaf(a[j].x, si, -b[j].x * sp) + EPS_F; sum_p = fmaf(t, t, sum_p);
        t = fmaf(a[j].y, si, -b[j].y * sp) + EPS_F; sum_p = fmaf(t, t, sum_p);
        t = fmaf(a[j].z, si, -b[j].z * sp) + EPS_F; sum_p = fmaf(t, t, sum_p);
        t = fmaf(a[j].w, si, -b[j].w * sp) + EPS_F; sum_p = fmaf(t, t, sum_p);
        t = fmaf(a[j].x, si, -c[j].x * sn) + EPS_F; sum_n = fmaf(t, t, sum_n);
        t = fmaf(a[j].y, si, -c[j].y * sn) + EPS_F; sum_n = fmaf(t, t, sum_n);
        t = fmaf(a[j].z, si, -c[j].z * sn) + EPS_F; sum_n = fmaf(t, t, sum_n);
        t = fmaf(a[j].w, si, -c[j].w * sn) + EPS_F; sum_n = fmaf(t, t, sum_n);
    }
    #pragma unroll
    for (int m = 1; m < 64; m <<= 1) {
        sum_p += __shfl_xor(sum_p, m, 64);
        sum_n += __shfl_xor(sum_n, m, 64);
    }

    if (lane == 0) {
        float d_pos = sqrtf(sum_p) + EPS_F;
        float d_neg = sqrtf(sum_n) + EPS_F;
        float mq = fmaxf(MARGIN_F - d_neg, EPS_F);
        losses[row] = d_pos * d_pos + mq * mq;
    }
}

__global__ __launch_bounds__(1024) void final_reduce_kernel(
    const float* __restrict__ losses,
    float*       __restrict__ out)
{
    const int tid  = threadIdx.x;
    const int lane = tid & 63;
    const int wid  = tid >> 6;   // 16 waves

    const float4* l4 = (const float4*)losses;   // NROWS/4 = 4096 float4
    float s = 0.0f;
    #pragma unroll
    for (int j = 0; j < 4; ++j) {
        float4 v = l4[tid + 1024 * j];
        s += v.x + v.y + v.z + v.w;
    }
    #pragma unroll
    for (int m = 1; m < 64; m <<= 1) s += __shfl_xor(s, m, 64);

    __shared__ float sm[16];
    if (lane == 0) sm[wid] = s;
    __syncthreads();
    if (tid == 0) {
        float total = 0.f;
        #pragma unroll
        for (int w = 0; w < 16; ++w) total += sm[w];
        out[0] = total / (2.0f * (float)NROWS);
    }
}

extern "C" void kernel_launch(void* const* d_in, const int* in_sizes, int n_in,
                              void* d_out, int out_size, void* d_ws, size_t ws_size,
                              hipStream_t stream) {
    const float* emb = (const float*)d_in[0];
    // d_in[1] = labels (unused by the loss itself)
    const int* pos = (const int*)d_in[2];
    const int* neg = (const int*)d_in[3];

    float* losses = (float*)d_ws;          // NROWS floats of scratch
    float* out    = (float*)d_out;

    row_loss_kernel<<<NROWS / 4, 256, 0, stream>>>(emb, pos, neg, losses);
    final_reduce_kernel<<<1, 1024, 0, stream>>>(losses, out);
}